// Round 11
// baseline (4040.660 us; speedup 1.0000x reference)
//
#include <hip/hip_runtime.h>
#include <hip/hip_bf16.h>

#define NEG 0.01f

using f32x4  = __attribute__((ext_vector_type(4))) float;
using bf16x8 = __attribute__((ext_vector_type(8))) short;

__device__ __forceinline__ unsigned short f2b(float f) {
  union { float f; unsigned int u; } v; v.f = f;
  unsigned int r = (v.u + 0x7fffu + ((v.u >> 16) & 1u)) >> 16;
  return (unsigned short)r;
}
__device__ __forceinline__ float b2f(unsigned int bits) {
  union { unsigned int u; float f; } v; v.u = bits << 16;
  return v.f;
}

__device__ __forceinline__ void gload16(const unsigned short* g, unsigned short* l) {
  __builtin_amdgcn_global_load_lds(
      (const __attribute__((address_space(1))) unsigned int*)g,
      (__attribute__((address_space(3))) unsigned int*)l, 16, 0, 0);
}

// ---- fp32 -> bf16 bulk convert ----
__global__ void k_cvt(const float* __restrict__ in, unsigned short* __restrict__ out, int n4) {
  int i = blockIdx.x * blockDim.x + threadIdx.x;
  int stride = gridDim.x * blockDim.x;
  for (; i < n4; i += stride) {
    float4 v = reinterpret_cast<const float4*>(in)[i];
    ushort4 o;
    o.x = f2b(v.x); o.y = f2b(v.y); o.z = f2b(v.z); o.w = f2b(v.w);
    reinterpret_cast<ushort4*>(out)[i] = o;
  }
}

// ---- triangular-masked weight convert, vectorized 8/thread.
//      anti=0: out[i][j] = (j>=i)?W[i][j]:0
//      anti=1: out[i][k] = (H-1-k>=i)?W[i][H-1-k]:0 ----
__global__ void k_cvt_tri(const float* __restrict__ W, unsigned short* __restrict__ out, int anti) {
  const int H = 2048;
  int i = blockIdx.x;
  const float* wr = W + (size_t)i * H;
  unsigned short* orow = out + (size_t)i * H;
  int j8 = threadIdx.x * 8;   // 256 threads x 8 = 2048
  unsigned short u[8];
  if (!anti) {
#pragma unroll
    for (int q = 0; q < 8; q++) {
      int j = j8 + q;
      u[q] = (j >= i) ? f2b(wr[j]) : (unsigned short)0;
    }
  } else {
#pragma unroll
    for (int q = 0; q < 8; q++) {
      int k = j8 + q, j = H - 1 - k;
      u[q] = (j >= i) ? f2b(wr[j]) : (unsigned short)0;
    }
  }
  ushort4 lo = {u[0], u[1], u[2], u[3]}, hi = {u[4], u[5], u[6], u[7]};
  *reinterpret_cast<ushort4*>(&orow[j8])     = lo;
  *reinterpret_cast<ushort4*>(&orow[j8 + 4]) = hi;
}

// ---- bf16 MFMA GEMM, C = lrelu(A @ B^T + bias), bf16 out.
// R10/R11: B-operand LOADED GLOBAL->REG (no LDS round-trip for B).
//   R9's wall was the LDS pipe: 128KB ds_read + 32KB write per block-K-tile
//   (4x4 wave dup) = 1790 cyc x 2 blocks = measured 3500 cyc/K-tile-pair.
//   B-frag lane layout (col=l&15, k=(l>>4)*8) is a direct 16B/lane global
//   load (4 lanes share a 64B line; adjacent K-tiles consume both halves of
//   each 128B L2 line).  LDS now holds A only: 2 x 16KB dbuf -> per-tile LDS
//   traffic halves.  B regs double-buffered (bu/bv), prefetched 1 K-tile
//   ahead, issue pinned by sched_barrier(0).
// vmcnt gating (A-stage 1 load/wave, B 4 loads/wave):
//   prologue: A0, B0, A1   -> gate vmcnt(1) leaves A1 in flight
//   tile t:   [gate vmcnt(1|0); barrier] [load B(t+1)] [A LDS reads; MFMA]
//             [lgkmcnt(0); barrier] [stage A(t+2)]
//   (B(t+1) loads are above the gate in count terms but their consumption
//   is data-dependency-gated by the compiler's counted waitcnt.)
// 512 persistent blocks = one balanced tri-pair each (bx,7-bx: 72 K-tiles),
// XCD-chunked.  LDS swizzle unchanged (0 conflicts, verified R5-R9).
// mode: 0=full K, 1=upper-tri (kstart=bcol), 2=anti (kend=K-bcol) ----
__launch_bounds__(1024, 2)
__global__ void k_gemm8(const unsigned short* __restrict__ A, int lda,
                        const unsigned short* __restrict__ B, int ldb,
                        const float* __restrict__ bias,
                        unsigned short* __restrict__ C, int ldc,
                        int K, int mode, int NB) {
  __shared__ unsigned short lds[16384];   // 32 KB: 2 x 16KB A bufs
  const int tid = threadIdx.x;
  const int w   = tid >> 6;    // 0..15
  const int l   = tid & 63;

  const int G = gridDim.x;     // 512
  const int P = blockIdx.x;
  const int b = (P & 7) * (G >> 3) + (P >> 3);   // XCD-contiguous ownership

  const int srow  = l >> 2;
  const int sperm = ((l & 3) - ((l >> 3) & 3)) & 3;
  const int rdoff = (l & 15) * 64 + ((((l >> 4) + ((l >> 1) & 7)) & 3) << 4);
  const int wm = w >> 2, wn = w & 3;   // 4x4 wave grid, wave tile 64x64

  const int npairs = NB * 4;
#pragma unroll 1
  for (int p = b; p < npairs; p += G) {
    const int by = p >> 2;
    const int pr = p & 3;
#pragma unroll 1
    for (int side = 0; side < 2; side++) {
      const int bx = side ? (7 - pr) : pr;   // deep tile first
      const int brow = by * 256;
      const int bcol = bx * 256;
      int kstart = 0, kend = K;
      if (mode == 1) kstart = bcol;
      else if (mode == 2) kend = K - bcol;
      const int nt = (kend - kstart) >> 5;   // K-tiles of 32, >= 1 (even)

      const unsigned short* Asrc = A + (size_t)(brow + w * 16 + srow) * lda + sperm * 8 + kstart;
      // B direct-load per-frag byte pointers (tile t adds t*64 bytes)
      const int bk = (l >> 4) * 8;
      const char* Bw0 = (const char*)(B + (size_t)(bcol + wn * 64 +  0 + (l & 15)) * ldb + bk + kstart);
      const char* Bw1 = (const char*)(B + (size_t)(bcol + wn * 64 + 16 + (l & 15)) * ldb + bk + kstart);
      const char* Bw2 = (const char*)(B + (size_t)(bcol + wn * 64 + 32 + (l & 15)) * ldb + bk + kstart);
      const char* Bw3 = (const char*)(B + (size_t)(bcol + wn * 64 + 48 + (l & 15)) * ldb + bk + kstart);

      auto stage_tile = [&](int tk, int bb) {
        gload16(Asrc + (tk << 5),
                (unsigned short*)((char*)lds + bb * 16384 + w * 1024));
      };

      f32x4 acc[4][4];
#pragma unroll
      for (int i = 0; i < 4; i++)
#pragma unroll
        for (int j = 0; j < 4; j++) acc[i][j] = (f32x4){0.f, 0.f, 0.f, 0.f};

      bf16x8 bu0, bu1, bu2, bu3, bv0, bv1, bv2, bv3;
      // prologue issue order: A0, B0(4), A1  (matches vmcnt(1) gate)
      stage_tile(0, 0);
      bu0 = *(const bf16x8*)(Bw0);
      bu1 = *(const bf16x8*)(Bw1);
      bu2 = *(const bf16x8*)(Bw2);
      bu3 = *(const bf16x8*)(Bw3);
      if (nt > 1) stage_tile(1, 1);

#define MROW(i, B0_, B1_, B2_, B3_)                                                            \
  acc[i][0] = __builtin_amdgcn_mfma_f32_16x16x32_bf16(af[i], B0_, acc[i][0], 0, 0, 0);         \
  acc[i][1] = __builtin_amdgcn_mfma_f32_16x16x32_bf16(af[i], B1_, acc[i][1], 0, 0, 0);         \
  acc[i][2] = __builtin_amdgcn_mfma_f32_16x16x32_bf16(af[i], B2_, acc[i][2], 0, 0, 0);         \
  acc[i][3] = __builtin_amdgcn_mfma_f32_16x16x32_bf16(af[i], B3_, acc[i][3], 0, 0, 0)

#define TILE_BODY(T, U0, U1, U2, U3, L0, L1, L2, L3)                                           \
  do {                                                                                         \
    const int bb = (T) & 1;                                                                    \
    const char* Ab = (const char*)lds + bb * 16384;                                            \
    if ((T) + 1 < nt) asm volatile("s_waitcnt vmcnt(1)" ::: "memory");                         \
    else              asm volatile("s_waitcnt vmcnt(0)" ::: "memory");                         \
    __builtin_amdgcn_s_barrier();                                                              \
    __builtin_amdgcn_sched_barrier(0);                                                         \
    if ((T) + 1 < nt) {                                                                        \
      const size_t to2 = (size_t)((T) + 1) * 64;                                               \
      L0 = *(const bf16x8*)(Bw0 + to2);                                                        \
      L1 = *(const bf16x8*)(Bw1 + to2);                                                        \
      L2 = *(const bf16x8*)(Bw2 + to2);                                                        \
      L3 = *(const bf16x8*)(Bw3 + to2);                                                        \
    }                                                                                          \
    __builtin_amdgcn_sched_barrier(0);                                                         \
    bf16x8 af[4];                                                                              \
    _Pragma("unroll")                                                                          \
    for (int i = 0; i < 4; i++)                                                                \
      af[i] = *(const bf16x8*)(Ab + (wm * 4 + i) * 1024 + rdoff);                              \
    __builtin_amdgcn_s_setprio(1);                                                             \
    MROW(0, U0, U1, U2, U3);                                                                   \
    MROW(1, U0, U1, U2, U3);                                                                   \
    MROW(2, U0, U1, U2, U3);                                                                   \
    MROW(3, U0, U1, U2, U3);                                                                   \
    __builtin_amdgcn_s_setprio(0);                                                             \
    asm volatile("s_waitcnt lgkmcnt(0)" ::: "memory");                                         \
    __builtin_amdgcn_s_barrier();                                                              \
    asm volatile("" ::: "memory");                                                             \
    if ((T) + 2 < nt) stage_tile((T) + 2, bb);                                                 \
  } while (0)

#pragma unroll 1
      for (int t = 0; t < nt; t += 2) {
        TILE_BODY(t, bu0, bu1, bu2, bu3, bv0, bv1, bv2, bv3);
        if (t + 1 < nt)
          TILE_BODY(t + 1, bv0, bv1, bv2, bv3, bu0, bu1, bu2, bu3);
      }
#undef TILE_BODY
#undef MROW

      // epilogue: bias + leaky-relu + bf16 store
      const int orow0 = brow + wm * 64 + ((l >> 4) << 2);
      const int ocol0 = bcol + wn * 64 + (l & 15);
#pragma unroll
      for (int j = 0; j < 4; j++) {
        const int col = ocol0 + j * 16;
        const float bv = bias[col];
#pragma unroll
        for (int i = 0; i < 4; i++) {
#pragma unroll
          for (int r = 0; r < 4; r++) {
            const int row = orow0 + i * 16 + r;
            float v = acc[i][j][r] + bv;
            v = v > 0.f ? v : NEG * v;
            C[(size_t)row * ldc + col] = f2b(v);
          }
        }
      }
    }
  }
}

// ---- final layer: out[n,0..2] = A[n,:] @ ow^T + ob ----
__global__ void k_out(const unsigned short* __restrict__ A,
                      const float* __restrict__ ow, const float* __restrict__ ob,
                      float* __restrict__ out) {
  const int H = 2048;
  int w = threadIdx.x >> 6, lane = threadIdx.x & 63;
  size_t n = (size_t)blockIdx.x * 4 + w;
  const unsigned short* a = A + n * H;
  float s0 = 0.f, s1 = 0.f, s2 = 0.f;
  for (int h0 = lane * 8; h0 < H; h0 += 512) {
    uint4 u = *reinterpret_cast<const uint4*>(&a[h0]);
    unsigned int uu[4] = {u.x, u.y, u.z, u.w};
#pragma unroll
    for (int q = 0; q < 4; q++) {
      int h = h0 + q * 2;
      float x0 = b2f(uu[q] & 0xffffu);
      float x1 = b2f(uu[q] >> 16);
      s0 += x0 * ow[h]         + x1 * ow[h + 1];
      s1 += x0 * ow[H + h]     + x1 * ow[H + h + 1];
      s2 += x0 * ow[2 * H + h] + x1 * ow[2 * H + h + 1];
    }
  }
#pragma unroll
  for (int off = 32; off > 0; off >>= 1) {
    s0 += __shfl_down(s0, off);
    s1 += __shfl_down(s1, off);
    s2 += __shfl_down(s2, off);
  }
  if (lane == 0) {
    out[n * 3 + 0] = s0 + ob[0];
    out[n * 3 + 1] = s1 + ob[1];
    out[n * 3 + 2] = s2 + ob[2];
  }
}

extern "C" void kernel_launch(void* const* d_in, const int* in_sizes, int n_in,
                              void* d_out, int out_size, void* d_ws, size_t ws_size,
                              hipStream_t stream) {
  const int N = 32768, H = 2048, INF_ = 64;
  const float* p      = (const float*)d_in[0];
  const float* init_w = (const float*)d_in[1];
  const float* init_b = (const float*)d_in[2];
  const float* w1     = (const float*)d_in[3];
  const float* b1     = (const float*)d_in[4];
  const float* w2     = (const float*)d_in[5];
  const float* b2     = (const float*)d_in[6];
  const float* w3     = (const float*)d_in[7];
  const float* b3     = (const float*)d_in[8];
  const float* ow     = (const float*)d_in[9];
  const float* ob     = (const float*)d_in[10];

  char* wsb = (char*)d_ws;
  size_t off = 0;
  auto alloc = [&](size_t bytes) -> char* {
    char* q = wsb + off;
    off += (bytes + 255) & ~(size_t)255;
    return q;
  };
  unsigned short* pb  = (unsigned short*)alloc((size_t)N * INF_ * 2);
  unsigned short* iwb = (unsigned short*)alloc((size_t)H * INF_ * 2);
  unsigned short* w1m = (unsigned short*)alloc((size_t)H * H * 2);
  unsigned short* w2m = (unsigned short*)alloc((size_t)H * H * 2);
  unsigned short* w3m = (unsigned short*)alloc((size_t)H * H * 2);

  size_t remain = (ws_size > off) ? (ws_size - off) : 0;
  long long ncll = (long long)(remain / ((size_t)H * 2 * 2));
  int Nc = (int)((ncll / 256) * 256);
  if (Nc > N) Nc = N;
  if (Nc < 256) return;  // ws too small: leave d_out poisoned (clean failure)

  unsigned short* bufA = (unsigned short*)(wsb + off);
  unsigned short* bufB = bufA + (size_t)Nc * H;

  k_cvt<<<2048, 256, 0, stream>>>(p, pb, N * INF_ / 4);
  k_cvt<<<32,   256, 0, stream>>>(init_w, iwb, H * INF_ / 4);
  k_cvt_tri<<<H, 256, 0, stream>>>(w1, w1m, 0);
  k_cvt_tri<<<H, 256, 0, stream>>>(w2, w2m, 0);
  k_cvt_tri<<<H, 256, 0, stream>>>(w3, w3m, 1);

  for (int n0 = 0; n0 < N; n0 += Nc) {
    int nc = (N - n0 < Nc) ? (N - n0) : Nc;
    int NB = nc / 256;
    // layer 0: K=64 (nt=2 per tile)
    k_gemm8<<<512, 1024, 0, stream>>>(pb + (size_t)n0 * INF_, INF_, iwb, INF_,
                                      init_b, bufA, H, INF_, 0, NB);
    // layer 1 (upper-tri)
    k_gemm8<<<512, 1024, 0, stream>>>(bufA, H, w1m, H, b1, bufB, H, H, 1, NB);
    // layer 2 (upper-tri; flip folded into w3m)
    k_gemm8<<<512, 1024, 0, stream>>>(bufB, H, w2m, H, b2, bufA, H, H, 1, NB);
    // layer 3 (anti-tri, pre-flipped weights)
    k_gemm8<<<512, 1024, 0, stream>>>(bufA, H, w3m, H, b3, bufB, H, H, 2, NB);
    // out head
    k_out<<<nc / 4, 256, 0, stream>>>(bufB, ow, ob, (float*)d_out + (size_t)n0 * 3);
  }
}

// Round 12
// 875.043 us; speedup vs baseline: 4.6177x; 4.6177x over previous
//
#include <hip/hip_runtime.h>
#include <hip/hip_bf16.h>

#define NEG 0.01f

using f32x4  = __attribute__((ext_vector_type(4))) float;
using bf16x8 = __attribute__((ext_vector_type(8))) short;

__device__ __forceinline__ unsigned short f2b(float f) {
  union { float f; unsigned int u; } v; v.f = f;
  unsigned int r = (v.u + 0x7fffu + ((v.u >> 16) & 1u)) >> 16;
  return (unsigned short)r;
}
__device__ __forceinline__ float b2f(unsigned int bits) {
  union { unsigned int u; float f; } v; v.u = bits << 16;
  return v.f;
}

__device__ __forceinline__ void gload16(const unsigned short* g, unsigned short* l) {
  __builtin_amdgcn_global_load_lds(
      (const __attribute__((address_space(1))) unsigned int*)g,
      (__attribute__((address_space(3))) unsigned int*)l, 16, 0, 0);
}

// ---- fp32 -> bf16 bulk convert ----
__global__ void k_cvt(const float* __restrict__ in, unsigned short* __restrict__ out, int n4) {
  int i = blockIdx.x * blockDim.x + threadIdx.x;
  int stride = gridDim.x * blockDim.x;
  for (; i < n4; i += stride) {
    float4 v = reinterpret_cast<const float4*>(in)[i];
    ushort4 o;
    o.x = f2b(v.x); o.y = f2b(v.y); o.z = f2b(v.z); o.w = f2b(v.w);
    reinterpret_cast<ushort4*>(out)[i] = o;
  }
}

// ---- triangular-masked weight convert, vectorized 8/thread ----
__global__ void k_cvt_tri(const float* __restrict__ W, unsigned short* __restrict__ out, int anti) {
  const int H = 2048;
  int i = blockIdx.x;
  const float* wr = W + (size_t)i * H;
  unsigned short* orow = out + (size_t)i * H;
  int j8 = threadIdx.x * 8;
  unsigned short u[8];
  if (!anti) {
#pragma unroll
    for (int q = 0; q < 8; q++) {
      int j = j8 + q;
      u[q] = (j >= i) ? f2b(wr[j]) : (unsigned short)0;
    }
  } else {
#pragma unroll
    for (int q = 0; q < 8; q++) {
      int k = j8 + q, j = H - 1 - k;
      u[q] = (j >= i) ? f2b(wr[j]) : (unsigned short)0;
    }
  }
  ushort4 lo = {u[0], u[1], u[2], u[3]}, hi = {u[4], u[5], u[6], u[7]};
  *reinterpret_cast<ushort4*>(&orow[j8])     = lo;
  *reinterpret_cast<ushort4*>(&orow[j8 + 4]) = hi;
}

// ---- deep-pipelined bf16 MFMA GEMM, C = lrelu(A @ B^T + bias), bf16 out.
// R12: ring-4 LDS pipeline, ONE barrier per K-tile, vmcnt never drained
// below 8 mid-loop (3 tiles of loads always in flight) — the m218/AITER
// counted-vmcnt mechanism, untried in R5-R11 (all were <=2-deep with >=2
// barriers + lgkm drains per tile = m233's 72%-overhead regime).
//   tile 256x256, 8 waves (2x4), wave 128x64, acc[8][4] = 128 AGPR,
//   BK=32, LDS = 4 slots x (A 16KB + B 16KB) = 128KB -> 1 block/CU,
//   launch_bounds(512,2) -> 256-reg cap (no spill; ~208 live).
// Ring safety (1 barrier/tile): stage(t+3) writes slot (t+3)&3, last read
// at tile t-1; a wave passes barrier t only after issuing tile t-1's MFMAs,
// whose operand reads must have retired (compiler lgkm data-deps) -> no
// read/write race.  Max wave skew = 1 tile.  Side-entry barrier protects
// slot reuse across consecutive output tiles.
// Gates: top of tile t, staged through min(t+2,nt-1):
//   rem>=2 -> vmcnt(8); rem==1 -> vmcnt(4); rem==0 -> vmcnt(0).
// Balanced persistent tri-pairs (bx,7-bx), XCD-chunked; verified LDS
// swizzle (0 conflicts): subtile chunk (r,g) at byte r*64+((g+(r>>1))&3)*16,
// write side via pre-rotated per-lane global source k-slot.
// mode: 0=full K, 1=upper-tri (kstart=bcol), 2=anti (kend=K-bcol) ----
__launch_bounds__(512, 2)
__global__ void k_gemm8(const unsigned short* __restrict__ A, int lda,
                        const unsigned short* __restrict__ B, int ldb,
                        const float* __restrict__ bias,
                        unsigned short* __restrict__ C, int ldc,
                        int K, int mode, int NB) {
  extern __shared__ unsigned short lds[];
  const int tid = threadIdx.x;
  const int w   = tid >> 6;    // 0..7
  const int l   = tid & 63;

  const int G = gridDim.x;     // 256
  const int P = blockIdx.x;
  const int b = (P & 7) * (G >> 3) + (P >> 3);   // XCD-contiguous ownership

  const int srow  = l >> 2;
  const int sperm = ((l & 3) - ((l >> 3) & 3)) & 3;
  const int rdoff = (l & 15) * 64 + ((((l >> 4) + ((l >> 1) & 7)) & 3) << 4);
  const int wm = w >> 2, wn = w & 3;   // 2x4 wave grid, wave tile 128x64

  const int npairs = NB * 4;
#pragma unroll 1
  for (int p = b; p < npairs; p += G) {
    const int by = p >> 2;
    const int pr = p & 3;
#pragma unroll 1
    for (int side = 0; side < 2; side++) {
      const int bx = side ? (7 - pr) : pr;   // deep tile first
      const int brow = by * 256;
      const int bcol = bx * 256;
      int kstart = 0, kend = K;
      if (mode == 1) kstart = bcol;
      else if (mode == 2) kend = K - bcol;
      const int nt = (kend - kstart) >> 5;   // K-tiles of 32, >= 1

      const unsigned short* Arow0 = A + (size_t)(brow + w * 16 + srow) * lda + sperm * 8 + kstart;
      const unsigned short* Arow1 = A + (size_t)(brow + (w + 8) * 16 + srow) * lda + sperm * 8 + kstart;
      const unsigned short* Brow0 = B + (size_t)(bcol + w * 16 + srow) * ldb + sperm * 8 + kstart;
      const unsigned short* Brow1 = B + (size_t)(bcol + (w + 8) * 16 + srow) * ldb + sperm * 8 + kstart;

      // wave stages 4KB per tile: A subtiles w, w+8 and B subtiles w, w+8
      auto stage_tile = [&](int tk) {
        const int kc = tk << 5;
        char* base = (char*)lds + (size_t)(tk & 3) * 32768;
        gload16(Arow0 + kc, (unsigned short*)(base + w * 1024));
        gload16(Arow1 + kc, (unsigned short*)(base + (w + 8) * 1024));
        gload16(Brow0 + kc, (unsigned short*)(base + 16384 + w * 1024));
        gload16(Brow1 + kc, (unsigned short*)(base + 16384 + (w + 8) * 1024));
      };

      f32x4 acc[8][4];
#pragma unroll
      for (int i = 0; i < 8; i++)
#pragma unroll
        for (int j = 0; j < 4; j++) acc[i][j] = (f32x4){0.f, 0.f, 0.f, 0.f};

      // side-entry barrier: previous side's last-tile readers are done
      __builtin_amdgcn_s_barrier();
      stage_tile(0);
      if (nt > 1) stage_tile(1);
      if (nt > 2) stage_tile(2);

#pragma unroll 1
      for (int t = 0; t < nt; t++) {
        const char* base = (const char*)lds + (size_t)(t & 3) * 32768;
        const char* Ab = base;
        const char* Bb = base + 16384;
        const int rem = nt - 1 - t;
        if (rem >= 2)      asm volatile("s_waitcnt vmcnt(8)" ::: "memory");
        else if (rem == 1) asm volatile("s_waitcnt vmcnt(4)" ::: "memory");
        else               asm volatile("s_waitcnt vmcnt(0)" ::: "memory");
        __builtin_amdgcn_s_barrier();          // the ONLY barrier per tile
        asm volatile("" ::: "memory");
        if (t + 3 < nt) stage_tile(t + 3);     // slot (t+3)&3: safe (see hdr)

        bf16x8 af[8], bfr[4];
#pragma unroll
        for (int i = 0; i < 8; i++)
          af[i] = *(const bf16x8*)(Ab + (wm * 8 + i) * 1024 + rdoff);
#pragma unroll
        for (int j = 0; j < 4; j++)
          bfr[j] = *(const bf16x8*)(Bb + (wn * 4 + j) * 1024 + rdoff);
        __builtin_amdgcn_s_setprio(1);
#pragma unroll
        for (int i = 0; i < 8; i++)
#pragma unroll
          for (int j = 0; j < 4; j++)
            acc[i][j] = __builtin_amdgcn_mfma_f32_16x16x32_bf16(af[i], bfr[j], acc[i][j], 0, 0, 0);
        __builtin_amdgcn_s_setprio(0);
      }

      // epilogue: bias + leaky-relu + bf16 store
      const int orow0 = brow + wm * 128 + ((l >> 4) << 2);
      const int ocol0 = bcol + wn * 64 + (l & 15);
#pragma unroll
      for (int j = 0; j < 4; j++) {
        const int col = ocol0 + j * 16;
        const float bv = bias[col];
#pragma unroll
        for (int i = 0; i < 8; i++) {
#pragma unroll
          for (int r = 0; r < 4; r++) {
            const int row = orow0 + i * 16 + r;
            float v = acc[i][j][r] + bv;
            v = v > 0.f ? v : NEG * v;
            C[(size_t)row * ldc + col] = f2b(v);
          }
        }
      }
    }
  }
}

// ---- final layer: out[n,0..2] = A[n,:] @ ow^T + ob ----
__global__ void k_out(const unsigned short* __restrict__ A,
                      const float* __restrict__ ow, const float* __restrict__ ob,
                      float* __restrict__ out) {
  const int H = 2048;
  int w = threadIdx.x >> 6, lane = threadIdx.x & 63;
  size_t n = (size_t)blockIdx.x * 4 + w;
  const unsigned short* a = A + n * H;
  float s0 = 0.f, s1 = 0.f, s2 = 0.f;
  for (int h0 = lane * 8; h0 < H; h0 += 512) {
    uint4 u = *reinterpret_cast<const uint4*>(&a[h0]);
    unsigned int uu[4] = {u.x, u.y, u.z, u.w};
#pragma unroll
    for (int q = 0; q < 4; q++) {
      int h = h0 + q * 2;
      float x0 = b2f(uu[q] & 0xffffu);
      float x1 = b2f(uu[q] >> 16);
      s0 += x0 * ow[h]         + x1 * ow[h + 1];
      s1 += x0 * ow[H + h]     + x1 * ow[H + h + 1];
      s2 += x0 * ow[2 * H + h] + x1 * ow[2 * H + h + 1];
    }
  }
#pragma unroll
  for (int off = 32; off > 0; off >>= 1) {
    s0 += __shfl_down(s0, off);
    s1 += __shfl_down(s1, off);
    s2 += __shfl_down(s2, off);
  }
  if (lane == 0) {
    out[n * 3 + 0] = s0 + ob[0];
    out[n * 3 + 1] = s1 + ob[1];
    out[n * 3 + 2] = s2 + ob[2];
  }
}

extern "C" void kernel_launch(void* const* d_in, const int* in_sizes, int n_in,
                              void* d_out, int out_size, void* d_ws, size_t ws_size,
                              hipStream_t stream) {
  const int N = 32768, H = 2048, INF_ = 64;
  const float* p      = (const float*)d_in[0];
  const float* init_w = (const float*)d_in[1];
  const float* init_b = (const float*)d_in[2];
  const float* w1     = (const float*)d_in[3];
  const float* b1     = (const float*)d_in[4];
  const float* w2     = (const float*)d_in[5];
  const float* b2     = (const float*)d_in[6];
  const float* w3     = (const float*)d_in[7];
  const float* b3     = (const float*)d_in[8];
  const float* ow     = (const float*)d_in[9];
  const float* ob     = (const float*)d_in[10];

  hipFuncSetAttribute((const void*)k_gemm8,
                      hipFuncAttributeMaxDynamicSharedMemorySize, 131072);

  char* wsb = (char*)d_ws;
  size_t off = 0;
  auto alloc = [&](size_t bytes) -> char* {
    char* q = wsb + off;
    off += (bytes + 255) & ~(size_t)255;
    return q;
  };
  unsigned short* pb  = (unsigned short*)alloc((size_t)N * INF_ * 2);
  unsigned short* iwb = (unsigned short*)alloc((size_t)H * INF_ * 2);
  unsigned short* w1m = (unsigned short*)alloc((size_t)H * H * 2);
  unsigned short* w2m = (unsigned short*)alloc((size_t)H * H * 2);
  unsigned short* w3m = (unsigned short*)alloc((size_t)H * H * 2);

  size_t remain = (ws_size > off) ? (ws_size - off) : 0;
  long long ncll = (long long)(remain / ((size_t)H * 2 * 2));
  int Nc = (int)((ncll / 256) * 256);
  if (Nc > N) Nc = N;
  if (Nc < 256) return;  // ws too small: leave d_out poisoned (clean failure)

  unsigned short* bufA = (unsigned short*)(wsb + off);
  unsigned short* bufB = bufA + (size_t)Nc * H;

  k_cvt<<<2048, 256, 0, stream>>>(p, pb, N * INF_ / 4);
  k_cvt<<<32,   256, 0, stream>>>(init_w, iwb, H * INF_ / 4);
  k_cvt_tri<<<H, 256, 0, stream>>>(w1, w1m, 0);
  k_cvt_tri<<<H, 256, 0, stream>>>(w2, w2m, 0);
  k_cvt_tri<<<H, 256, 0, stream>>>(w3, w3m, 1);

  for (int n0 = 0; n0 < N; n0 += Nc) {
    int nc = (N - n0 < Nc) ? (N - n0) : Nc;
    int NB = nc / 256;
    // layer 0: K=64 (nt=2 per tile)
    k_gemm8<<<256, 512, 131072, stream>>>(pb + (size_t)n0 * INF_, INF_, iwb, INF_,
                                          init_b, bufA, H, INF_, 0, NB);
    // layer 1 (upper-tri)
    k_gemm8<<<256, 512, 131072, stream>>>(bufA, H, w1m, H, b1, bufB, H, H, 1, NB);
    // layer 2 (upper-tri; flip folded into w3m)
    k_gemm8<<<256, 512, 131072, stream>>>(bufB, H, w2m, H, b2, bufA, H, H, 1, NB);
    // layer 3 (anti-tri, pre-flipped weights)
    k_gemm8<<<256, 512, 131072, stream>>>(bufA, H, w3m, H, b3, bufB, H, H, 2, NB);
    // out head
    k_out<<<nc / 4, 256, 0, stream>>>(bufB, ow, ob, (float*)d_out + (size_t)n0 * 3);
  }
}